// Round 4
// baseline (758.547 us; speedup 1.0000x reference)
//
#include <hip/hip_runtime.h>
#include <hip/hip_bf16.h>

#define M_ROWS 16384
#define N_CODES 8192
#define DDIM    512

typedef unsigned int u32;
typedef unsigned long long u64;
typedef unsigned short u16;
typedef __attribute__((ext_vector_type(8))) short short8;     // 8 bf16 = 4 VGPRs
typedef __attribute__((ext_vector_type(16))) float f32x16;    // 32x32 accumulator

__device__ __forceinline__ u32 float_to_ordered(float f) {
    u32 u = __float_as_uint(f);
    return (u & 0x80000000u) ? ~u : (u | 0x80000000u);
}

__device__ __forceinline__ u16 bf16_rne(float x) {
    u32 u = __float_as_uint(x);
    u32 r = u + 0x7FFFu + ((u >> 16) & 1u);
    return (u16)(r >> 16);
}

__device__ __forceinline__ void gl_lds16(const void* g, void* l) {
    __builtin_amdgcn_global_load_lds((const __attribute__((address_space(1))) u32*)g,
                                     (__attribute__((address_space(3))) u32*)l,
                                     16, 0, 0);
}

__device__ __forceinline__ u64 umin64(u64 a, u64 b) { return a < b ? a : b; }

// ---------------------------------------------------------------------------
// Kernel 1: fused prep. Blocks [0,16384): split z -> (hi,lo) bf16 (4 f32/thr),
// plus packed-init and loss-init. Blocks [16384,18432): split emb + ||e||^2
// (one wave per code).
// ---------------------------------------------------------------------------
__global__ __launch_bounds__(256) void vq_prep(
    const float4* __restrict__ z4, ushort4* __restrict__ zh, ushort4* __restrict__ zl,
    const float* __restrict__ emb, ushort4* __restrict__ eh, ushort4* __restrict__ el,
    float* __restrict__ e_norms, u64* __restrict__ packed,
    float* __restrict__ out_loss) {
    int b = blockIdx.x;
    if (b < (M_ROWS * DDIM) / 1024) {
        int i = b * 256 + threadIdx.x;
        float4 v = z4[i];
        ushort4 h, l;
        h.x = bf16_rne(v.x); h.y = bf16_rne(v.y); h.z = bf16_rne(v.z); h.w = bf16_rne(v.w);
        l.x = bf16_rne(v.x - __uint_as_float((u32)h.x << 16));
        l.y = bf16_rne(v.y - __uint_as_float((u32)h.y << 16));
        l.z = bf16_rne(v.z - __uint_as_float((u32)h.z << 16));
        l.w = bf16_rne(v.w - __uint_as_float((u32)h.w << 16));
        zh[i] = h; zl[i] = l;
        if (i < M_ROWS) packed[i] = 0xFFFFFFFFFFFFFFFFull;
        if (i == 0) out_loss[0] = 0.0f;
    } else {
        int wave = threadIdx.x >> 6;
        int lane = threadIdx.x & 63;
        int code = (b - (M_ROWS * DDIM) / 1024) * 4 + wave;
        const float4* ep = (const float4*)(emb + (size_t)code * DDIM);
        size_t base4 = (size_t)code * (DDIM / 4);
        float s = 0.f;
        #pragma unroll
        for (int j = 0; j < 2; ++j) {
            int c = lane + 64 * j;
            float4 e = ep[c];
            s += e.x * e.x + e.y * e.y + e.z * e.z + e.w * e.w;
            ushort4 h, l;
            h.x = bf16_rne(e.x); h.y = bf16_rne(e.y); h.z = bf16_rne(e.z); h.w = bf16_rne(e.w);
            l.x = bf16_rne(e.x - __uint_as_float((u32)h.x << 16));
            l.y = bf16_rne(e.y - __uint_as_float((u32)h.y << 16));
            l.z = bf16_rne(e.z - __uint_as_float((u32)h.z << 16));
            l.w = bf16_rne(e.w - __uint_as_float((u32)h.w << 16));
            eh[base4 + c] = h; el[base4 + c] = l;
        }
        #pragma unroll
        for (int off = 32; off; off >>= 1) s += __shfl_down(s, off, 64);
        if (lane == 0) e_norms[code] = s;
    }
}

// ---------------------------------------------------------------------------
// Kernel 2: MFMA distance GEMM + fused argmin.
// 32x32x16 bf16 MFMA, 3-product split-bf16 (hi*hi + hi*lo + lo*hi).
// A (z) fragments loaded DIRECTLY global->VGPR (no LDS round trip; L2-served,
// grid.x = col-block so consecutive blocks reuse one 256KB A slice).
// B (codes) staged to LDS via global_load_lds width=16.
// Block tile 128x128, 4 waves (2x2), wave tile 64x64 = 2x2 frags of 32x32.
// ---------------------------------------------------------------------------
__global__ __launch_bounds__(256) void vq_mfma_argmin(
    const u16* __restrict__ z_hi, const u16* __restrict__ z_lo,
    const u16* __restrict__ e_hi, const u16* __restrict__ e_lo,
    const float* __restrict__ e_norms,
    u64* __restrict__ packed) {
    __shared__ __align__(16) u16 ldsBh[128][32];   // 8 KB
    __shared__ __align__(16) u16 ldsBl[128][32];   // 8 KB
    __shared__ u64 redL[2][128];                   // 2 KB

    const int tid  = threadIdx.x;
    const int wave = tid >> 6;
    const int lane = tid & 63;
    const int wm   = wave & 1;
    const int wn   = wave >> 1;
    const int col0 = blockIdx.x * 128;   // x = col-block: A reused across x-sweep
    const int row0 = blockIdx.y * 128;

    // ---- B staging pattern (wave-uniform base + lane*16) ----
    const int srow = (wave << 5) + (lane >> 2);     // +16*s
    const int scol = (lane & 3) << 3;
    const u16* gBh = e_hi + (size_t)(col0 + srow) * DDIM + scol;
    const u16* gBl = e_lo + (size_t)(col0 + srow) * DDIM + scol;

    // ---- A direct-load bases: lane -> row (lane&31), k-chunk (lane>>5)*8 ----
    const int arow = row0 + (wm << 6) + (lane & 31);
    const int ka   = (lane >> 5) << 3;
    const u16* aH0 = z_hi + (size_t)arow * DDIM + ka;            // m-frag 0
    const u16* aH1 = aH0 + (size_t)32 * DDIM;                    // m-frag 1
    const u16* aL0 = z_lo + (size_t)arow * DDIM + ka;
    const u16* aL1 = aL0 + (size_t)32 * DDIM;

    // ---- B fragment read coords ----
    const int fn = (wn << 6) + (lane & 31);
    const int fk = (lane >> 5) << 3;

    f32x16 acc[2][2] = {};

    for (int it = 0; it < 16; ++it) {
        const int d0 = it << 5;
        __syncthreads();   // previous iter's B reads complete before overwrite
        #pragma unroll
        for (int s = 0; s < 2; ++s) {
            const size_t go = (size_t)d0 + (size_t)s * 16 * DDIM;
            const int lr = (wave << 5) + (s << 4);
            gl_lds16(gBh + go, &ldsBh[lr][0]);
            gl_lds16(gBl + go, &ldsBl[lr][0]);
        }
        // A loads issued before the barrier: latency hides under vmcnt(0) drain
        short8 a_h[2][2], a_l[2][2];   // [m-frag][k-step]
        #pragma unroll
        for (int s = 0; s < 2; ++s) {
            const int o = d0 + s * 16;
            a_h[0][s] = *(const short8*)(aH0 + o);
            a_h[1][s] = *(const short8*)(aH1 + o);
            a_l[0][s] = *(const short8*)(aL0 + o);
            a_l[1][s] = *(const short8*)(aL1 + o);
        }
        __syncthreads();   // B staged (drains vmcnt, incl. A loads)

        #pragma unroll
        for (int s = 0; s < 2; ++s) {
            short8 b_h[2], b_l[2];
            #pragma unroll
            for (int j = 0; j < 2; ++j) {
                b_h[j] = *(const short8*)&ldsBh[fn + j * 32][s * 16 + fk];
                b_l[j] = *(const short8*)&ldsBl[fn + j * 32][s * 16 + fk];
            }
            #pragma unroll
            for (int i = 0; i < 2; ++i)
                #pragma unroll
                for (int j = 0; j < 2; ++j) {
                    acc[i][j] = __builtin_amdgcn_mfma_f32_32x32x16_bf16(a_h[i][s], b_h[j], acc[i][j], 0, 0, 0);
                    acc[i][j] = __builtin_amdgcn_mfma_f32_32x32x16_bf16(a_h[i][s], b_l[j], acc[i][j], 0, 0, 0);
                    acc[i][j] = __builtin_amdgcn_mfma_f32_32x32x16_bf16(a_l[i][s], b_h[j], acc[i][j], 0, 0, 0);
                }
        }
    }

    // ---- epilogue: 32x32 C layout: col = lane&31, row = (r&3)+8*(r>>2)+4*(lane>>5)
    const int cn   = lane & 31;
    const int half = lane >> 5;
    float en[2];
    #pragma unroll
    for (int j = 0; j < 2; ++j) en[j] = e_norms[col0 + (wn << 6) + j * 32 + cn];

    #pragma unroll
    for (int i = 0; i < 2; ++i)
        #pragma unroll
        for (int r = 0; r < 16; ++r) {
            const int rowl = (wm << 6) + (i << 5) + (r & 3) + ((r >> 2) << 3) + (half << 2);
            float d0v = en[0] - 2.0f * acc[i][0][r];
            float d1v = en[1] - 2.0f * acc[i][1][r];
            u64 p0 = ((u64)float_to_ordered(d0v) << 32) | (u32)(col0 + (wn << 6) + cn);
            u64 p1 = ((u64)float_to_ordered(d1v) << 32) | (u32)(col0 + (wn << 6) + 32 + cn);
            u64 best = umin64(p0, p1);
            #pragma unroll
            for (int off = 1; off < 32; off <<= 1)
                best = umin64(best, __shfl_xor(best, off, 64));
            if (cn == 0) redL[wn][rowl] = best;
        }
    __syncthreads();
    if (tid < 128) {
        u64 m = umin64(redL[0][tid], redL[1][tid]);
        atomicMin(&packed[row0 + tid], m);
    }
}

// ---------------------------------------------------------------------------
// Kernel 3: gather quantized rows, float indices, loss via block atomicAdd.
// ---------------------------------------------------------------------------
__global__ __launch_bounds__(256) void vq_gather_loss(
    const float* __restrict__ z, const float* __restrict__ emb,
    const u64* __restrict__ packed,
    float* __restrict__ out_q, float* __restrict__ out_idx,
    float* __restrict__ out_loss) {
    int wave = threadIdx.x >> 6;
    int lane = threadIdx.x & 63;
    int row  = blockIdx.x * 4 + wave;

    int idx = (int)(packed[row] & 0xFFFFFFFFull);
    const float4* qp = (const float4*)(emb + (size_t)idx * DDIM);
    const float4* zp = (const float4*)(z + (size_t)row * DDIM);
    float4*       op = (float4*)(out_q + (size_t)row * DDIM);

    float local = 0.f;
    #pragma unroll
    for (int j = 0; j < 2; ++j) {
        int c = lane + 64 * j;
        float4 q = qp[c];
        float4 v = zp[c];
        op[c] = q;
        float dx = v.x - q.x, dy = v.y - q.y, dz = v.z - q.z, dw = v.w - q.w;
        local += dx * dx + dy * dy + dz * dz + dw * dw;
    }
    #pragma unroll
    for (int off = 32; off; off >>= 1) local += __shfl_down(local, off, 64);

    __shared__ float wsum[4];
    if (lane == 0) { wsum[wave] = local; out_idx[row] = (float)idx; }
    __syncthreads();
    if (threadIdx.x == 0)
        atomicAdd(out_loss, (0.25f / ((float)M_ROWS * (float)DDIM)) *
                                (wsum[0] + wsum[1] + wsum[2] + wsum[3]));
}

extern "C" void kernel_launch(void* const* d_in, const int* in_sizes, int n_in,
                              void* d_out, int out_size, void* d_ws, size_t ws_size,
                              hipStream_t stream) {
    const float* z   = (const float*)d_in[0];   // [16384, 512]
    const float* emb = (const float*)d_in[1];   // [8192, 512]

    float* out      = (float*)d_out;
    float* out_q    = out;
    float* out_idx  = out + (size_t)M_ROWS * DDIM;
    float* out_loss = out + (size_t)M_ROWS * DDIM + M_ROWS;

    char* ws = (char*)d_ws;
    u64*   packed  = (u64*)ws;                    // 128 KB
    float* e_norms = (float*)(ws + 131072);       // 32 KB

    const size_t zbytes = (size_t)M_ROWS * DDIM * 2;   // 16 MB per half
    const size_t ebytes = (size_t)N_CODES * DDIM * 2;  // 8 MB per half
    const size_t base = 196608;
    u16 *z_hi, *z_lo, *e_hi, *e_lo;
    if (ws_size >= base + 2 * zbytes + 2 * ebytes) {
        z_hi = (u16*)(ws + base);
        z_lo = (u16*)(ws + base + zbytes);
        e_hi = (u16*)(ws + base + 2 * zbytes);
        e_lo = (u16*)(ws + base + 2 * zbytes + ebytes);
    } else {
        // stash z halves in out_q region (32 MB, rewritten by gather afterwards)
        z_hi = (u16*)out_q;
        z_lo = (u16*)((char*)out_q + zbytes);
        e_hi = (u16*)(ws + base);
        e_lo = (u16*)(ws + base + ebytes);
    }

    const int zblocks = (M_ROWS * DDIM) / 1024;      // 16384
    const int eblocks = N_CODES / 4;                 // 2048
    vq_prep<<<zblocks + eblocks, 256, 0, stream>>>(
        (const float4*)z, (ushort4*)z_hi, (ushort4*)z_lo,
        emb, (ushort4*)e_hi, (ushort4*)e_lo, e_norms, packed, out_loss);

    vq_mfma_argmin<<<dim3(N_CODES / 128, M_ROWS / 128), 256, 0, stream>>>(
        z_hi, z_lo, e_hi, e_lo, e_norms, packed);

    vq_gather_loss<<<M_ROWS / 4, 256, 0, stream>>>(z, emb, packed, out_q, out_idx,
                                                   out_loss);
}

// Round 5
// 723.327 us; speedup vs baseline: 1.0487x; 1.0487x over previous
//
#include <hip/hip_runtime.h>
#include <hip/hip_bf16.h>

#define M_ROWS 16384
#define N_CODES 8192
#define DDIM    512
#define NCHUNK  256          // 32-code chunks per row
#define QCAP    524288       // candidate queue capacity (23x expected)
#define MARGIN  4.0f         // coarse-vs-exact distance margin

typedef unsigned int u32;
typedef unsigned long long u64;
typedef unsigned short u16;
typedef __attribute__((ext_vector_type(8))) short short8;   // 8 bf16 = 4 VGPRs
typedef __attribute__((ext_vector_type(4))) float f32x4;

__device__ __forceinline__ u32 float_to_ordered(float f) {
    u32 u = __float_as_uint(f);
    return (u & 0x80000000u) ? ~u : (u | 0x80000000u);
}

__device__ __forceinline__ u16 bf16_rne(float x) {
    u32 u = __float_as_uint(x);
    u32 r = u + 0x7FFFu + ((u >> 16) & 1u);
    return (u16)(r >> 16);
}

__device__ __forceinline__ void gl_lds16(const void* g, void* l) {
    __builtin_amdgcn_global_load_lds((const __attribute__((address_space(1))) u32*)g,
                                     (__attribute__((address_space(3))) u32*)l,
                                     16, 0, 0);
}

__device__ __forceinline__ u64 umin64(u64 a, u64 b) { return a < b ? a : b; }

// ---------------------------------------------------------------------------
// Kernel 1: prep. Blocks [0,16384): z -> z_hi bf16, init packed/count/loss.
// Blocks [16384,18432): emb -> e_hi bf16 + ||e||^2 (one wave per code).
// ---------------------------------------------------------------------------
__global__ __launch_bounds__(256) void vq_prep(
    const float4* __restrict__ z4, ushort4* __restrict__ zh,
    const float* __restrict__ emb, ushort4* __restrict__ eh,
    float* __restrict__ e_norms, u64* __restrict__ packed,
    u32* __restrict__ count, float* __restrict__ out_loss) {
    int b = blockIdx.x;
    if (b < (M_ROWS * DDIM) / 1024) {
        int i = b * 256 + threadIdx.x;
        float4 v = z4[i];
        ushort4 h;
        h.x = bf16_rne(v.x); h.y = bf16_rne(v.y);
        h.z = bf16_rne(v.z); h.w = bf16_rne(v.w);
        zh[i] = h;
        if (i < M_ROWS) packed[i] = 0xFFFFFFFFFFFFFFFFull;
        if (i == 0) { out_loss[0] = 0.0f; count[0] = 0u; }
    } else {
        int wave = threadIdx.x >> 6;
        int lane = threadIdx.x & 63;
        int code = (b - (M_ROWS * DDIM) / 1024) * 4 + wave;
        const float4* ep = (const float4*)(emb + (size_t)code * DDIM);
        size_t base4 = (size_t)code * (DDIM / 4);
        float s = 0.f;
        #pragma unroll
        for (int j = 0; j < 2; ++j) {
            int c = lane + 64 * j;
            float4 e = ep[c];
            s += e.x * e.x + e.y * e.y + e.z * e.z + e.w * e.w;
            ushort4 h;
            h.x = bf16_rne(e.x); h.y = bf16_rne(e.y);
            h.z = bf16_rne(e.z); h.w = bf16_rne(e.w);
            eh[base4 + c] = h;
        }
        #pragma unroll
        for (int off = 32; off; off >>= 1) s += __shfl_down(s, off, 64);
        if (lane == 0) e_norms[code] = s;
    }
}

// ---------------------------------------------------------------------------
// Kernel 2: phase-1 coarse GEMM (hi*hi only) + per-(row, 32-col-chunk) minima.
// Round-2 verified structure: 128x128 tile, BK=32, 4 waves 2x2, 4x4 frags of
// 16x16x32. Each (row,chunk) owned by exactly one wave -> plain stores.
// ---------------------------------------------------------------------------
__global__ __launch_bounds__(256) void vq_phase1(
    const u16* __restrict__ z_hi, const u16* __restrict__ e_hi,
    const float* __restrict__ e_norms,
    float* __restrict__ chunkmin) {
    __shared__ __align__(16) u16 ldsA[128][32];   // 8 KB
    __shared__ __align__(16) u16 ldsB[128][32];   // 8 KB

    const int tid  = threadIdx.x;
    const int wave = tid >> 6;
    const int lane = tid & 63;
    const int wm   = wave & 1;
    const int wn   = wave >> 1;
    const int row0 = blockIdx.x * 128;
    const int col0 = blockIdx.y * 128;

    const int srow = (wave << 5) + (lane >> 2);
    const int scol = (lane & 3) << 3;
    const u16* gA = z_hi + (size_t)(row0 + srow) * DDIM + scol;
    const u16* gB = e_hi + (size_t)(col0 + srow) * DDIM + scol;

    const int fm = (wm << 6) + (lane & 15);
    const int fn = (wn << 6) + (lane & 15);
    const int fk = (lane >> 4) << 3;

    f32x4 acc[4][4] = {};

    for (int it = 0; it < 16; ++it) {
        const int d0 = it << 5;
        __syncthreads();
        #pragma unroll
        for (int s = 0; s < 2; ++s) {
            const size_t go = (size_t)d0 + (size_t)s * 16 * DDIM;
            const int lr = (wave << 5) + (s << 4);
            gl_lds16(gA + go, &ldsA[lr][0]);
            gl_lds16(gB + go, &ldsB[lr][0]);
        }
        __syncthreads();

        short8 ah[4], bh[4];
        #pragma unroll
        for (int i = 0; i < 4; ++i) ah[i] = *(const short8*)&ldsA[fm + i * 16][fk];
        #pragma unroll
        for (int j = 0; j < 4; ++j) bh[j] = *(const short8*)&ldsB[fn + j * 16][fk];
        #pragma unroll
        for (int i = 0; i < 4; ++i)
            #pragma unroll
            for (int j = 0; j < 4; ++j)
                acc[i][j] = __builtin_amdgcn_mfma_f32_16x16x32_bf16(ah[i], bh[j], acc[i][j], 0, 0, 0);
    }

    // epilogue: C layout col = lane&15, row = (lane>>4)*4 + reg.
    // cols j=0,1 -> chunk wn*2 ; j=2,3 -> chunk wn*2+1 (32 cols each).
    const int cn = lane & 15;
    const int cg = lane >> 4;
    float en[4];
    #pragma unroll
    for (int j = 0; j < 4; ++j) en[j] = e_norms[col0 + (wn << 6) + j * 16 + cn];

    #pragma unroll
    for (int i = 0; i < 4; ++i)
        #pragma unroll
        for (int r = 0; r < 4; ++r) {
            float d0v = en[0] - 2.0f * acc[i][0][r];
            float d1v = en[1] - 2.0f * acc[i][1][r];
            float d2v = en[2] - 2.0f * acc[i][2][r];
            float d3v = en[3] - 2.0f * acc[i][3][r];
            float m01 = fminf(d0v, d1v);
            float m23 = fminf(d2v, d3v);
            #pragma unroll
            for (int off = 1; off < 16; off <<= 1) {
                m01 = fminf(m01, __shfl_xor(m01, off, 64));
                m23 = fminf(m23, __shfl_xor(m23, off, 64));
            }
            if (cn == 0) {
                int row_g = row0 + (wm << 6) + i * 16 + (cg << 2) + r;
                int cbase = row_g * NCHUNK + (blockIdx.y << 2) + (wn << 1);
                chunkmin[cbase]     = m01;
                chunkmin[cbase + 1] = m23;
            }
        }
}

// ---------------------------------------------------------------------------
// Kernel 3: candidate selection. One wave per row: global coarse min over 256
// chunk minima; enqueue chunks within MARGIN of it.
// ---------------------------------------------------------------------------
__global__ __launch_bounds__(256) void vq_candsel(
    const float* __restrict__ chunkmin,
    u32* __restrict__ count, u32* __restrict__ queue) {
    int wave = threadIdx.x >> 6;
    int lane = threadIdx.x & 63;
    int row  = blockIdx.x * 4 + wave;

    const float4* cm4 = (const float4*)(chunkmin + (size_t)row * NCHUNK);
    float4 v = cm4[lane];
    float m = fminf(fminf(v.x, v.y), fminf(v.z, v.w));
    #pragma unroll
    for (int off = 1; off < 64; off <<= 1) m = fminf(m, __shfl_xor(m, off, 64));
    float thr = m + MARGIN;

    float vv[4] = {v.x, v.y, v.z, v.w};
    #pragma unroll
    for (int c = 0; c < 4; ++c) {
        if (vv[c] <= thr) {
            u32 pos = atomicAdd(count, 1u);
            if (pos < QCAP) queue[pos] = ((u32)row << 8) | (u32)(lane * 4 + c);
        }
    }
}

// ---------------------------------------------------------------------------
// Kernel 4: phase-2 exact fp32 re-evaluation of candidate chunks -> packed
// argmin. One block per queue item (strided); wave w handles 8 codes.
// ---------------------------------------------------------------------------
__global__ __launch_bounds__(256) void vq_phase2(
    const float* __restrict__ z, const float* __restrict__ emb,
    const float* __restrict__ e_norms,
    const u32* __restrict__ count, const u32* __restrict__ queue,
    u64* __restrict__ packed) {
    int wave = threadIdx.x >> 6;
    int lane = threadIdx.x & 63;
    u32 total = *count;
    if (total > QCAP) total = QCAP;

    for (u32 it = blockIdx.x; it < total; it += gridDim.x) {
        u32 q = queue[it];
        int row = (int)(q >> 8);
        int c0  = (int)(q & 255u) * 32 + wave * 8;
        const float4* z4 = (const float4*)(z + (size_t)row * DDIM);
        float4 zA = z4[2 * lane];
        float4 zB = z4[2 * lane + 1];
        u64 best = 0xFFFFFFFFFFFFFFFFull;
        #pragma unroll
        for (int k = 0; k < 8; ++k) {
            int c = c0 + k;
            const float4* e4 = (const float4*)(emb + (size_t)c * DDIM);
            float4 eA = e4[2 * lane];
            float4 eB = e4[2 * lane + 1];
            float p = zA.x * eA.x + zA.y * eA.y + zA.z * eA.z + zA.w * eA.w
                    + zB.x * eB.x + zB.y * eB.y + zB.z * eB.z + zB.w * eB.w;
            #pragma unroll
            for (int off = 1; off < 64; off <<= 1) p += __shfl_xor(p, off, 64);
            float dist = e_norms[c] - 2.0f * p;
            best = umin64(best, ((u64)float_to_ordered(dist) << 32) | (u32)c);
        }
        if (lane == 0) atomicMin(&packed[row], best);
    }
}

// ---------------------------------------------------------------------------
// Kernel 5: gather quantized rows, float indices, loss via block atomicAdd.
// ---------------------------------------------------------------------------
__global__ __launch_bounds__(256) void vq_gather_loss(
    const float* __restrict__ z, const float* __restrict__ emb,
    const u64* __restrict__ packed,
    float* __restrict__ out_q, float* __restrict__ out_idx,
    float* __restrict__ out_loss) {
    int wave = threadIdx.x >> 6;
    int lane = threadIdx.x & 63;
    int row  = blockIdx.x * 4 + wave;

    int idx = (int)(packed[row] & 0xFFFFFFFFull);
    const float4* qp = (const float4*)(emb + (size_t)idx * DDIM);
    const float4* zp = (const float4*)(z + (size_t)row * DDIM);
    float4*       op = (float4*)(out_q + (size_t)row * DDIM);

    float local = 0.f;
    #pragma unroll
    for (int j = 0; j < 2; ++j) {
        int c = lane + 64 * j;
        float4 qv = qp[c];
        float4 v = zp[c];
        op[c] = qv;
        float dx = v.x - qv.x, dy = v.y - qv.y, dz = v.z - qv.z, dw = v.w - qv.w;
        local += dx * dx + dy * dy + dz * dz + dw * dw;
    }
    #pragma unroll
    for (int off = 32; off; off >>= 1) local += __shfl_down(local, off, 64);

    __shared__ float wsum[4];
    if (lane == 0) { wsum[wave] = local; out_idx[row] = (float)idx; }
    __syncthreads();
    if (threadIdx.x == 0)
        atomicAdd(out_loss, (0.25f / ((float)M_ROWS * (float)DDIM)) *
                                (wsum[0] + wsum[1] + wsum[2] + wsum[3]));
}

extern "C" void kernel_launch(void* const* d_in, const int* in_sizes, int n_in,
                              void* d_out, int out_size, void* d_ws, size_t ws_size,
                              hipStream_t stream) {
    const float* z   = (const float*)d_in[0];   // [16384, 512]
    const float* emb = (const float*)d_in[1];   // [8192, 512]

    float* out      = (float*)d_out;
    float* out_q    = out;
    float* out_idx  = out + (size_t)M_ROWS * DDIM;
    float* out_loss = out + (size_t)M_ROWS * DDIM + M_ROWS;

    char* ws = (char*)d_ws;
    u64*   packed   = (u64*)ws;                           // 128 KB
    float* e_norms  = (float*)(ws + 131072);              // 32 KB
    u32*   count    = (u32*)(ws + 163840);                // 256 B slot
    float* chunkmin = (float*)(ws + 164096);              // 16 MB
    u32*   queue    = (u32*)(ws + 164096 + 16777216);     // 2 MB
    size_t tail     = 164096 + 16777216 + (size_t)QCAP * 4;

    const size_t zbytes = (size_t)M_ROWS * DDIM * 2;   // 16 MB
    const size_t ebytes = (size_t)N_CODES * DDIM * 2;  // 8 MB
    u16 *z_hi, *e_hi;
    if (ws_size >= tail + zbytes + ebytes) {
        z_hi = (u16*)(ws + tail);
        e_hi = (u16*)(ws + tail + zbytes);
    } else {
        // stash bf16 copies in out_q region (33.5 MB >= 24 MB); gather
        // rewrites out_q afterwards.
        z_hi = (u16*)out_q;
        e_hi = (u16*)((char*)out_q + zbytes);
    }

    const int zblocks = (M_ROWS * DDIM) / 1024;      // 16384
    const int eblocks = N_CODES / 4;                 // 2048
    vq_prep<<<zblocks + eblocks, 256, 0, stream>>>(
        (const float4*)z, (ushort4*)z_hi,
        emb, (ushort4*)e_hi, e_norms, packed, count, out_loss);

    vq_phase1<<<dim3(M_ROWS / 128, N_CODES / 128), 256, 0, stream>>>(
        z_hi, e_hi, e_norms, chunkmin);

    vq_candsel<<<M_ROWS / 4, 256, 0, stream>>>(chunkmin, count, queue);

    vq_phase2<<<2048, 256, 0, stream>>>(z, emb, e_norms, count, queue, packed);

    vq_gather_loss<<<M_ROWS / 4, 256, 0, stream>>>(z, emb, packed, out_q, out_idx,
                                                   out_loss);
}

// Round 6
// 450.124 us; speedup vs baseline: 1.6852x; 1.6069x over previous
//
#include <hip/hip_runtime.h>
#include <hip/hip_bf16.h>

#define M_ROWS 16384
#define N_CODES 8192
#define DDIM    512
#define NCHUNK  256          // 32-code chunks per row
#define MARGIN  4.0f         // coarse-vs-exact distance margin (validated R5)

typedef unsigned int u32;
typedef unsigned long long u64;
typedef unsigned short u16;
typedef __attribute__((ext_vector_type(8))) short short8;   // 8 bf16 = 4 VGPRs
typedef __attribute__((ext_vector_type(4))) float f32x4;

__device__ __forceinline__ u32 float_to_ordered(float f) {
    u32 u = __float_as_uint(f);
    return (u & 0x80000000u) ? ~u : (u | 0x80000000u);
}

__device__ __forceinline__ u16 bf16_rne(float x) {
    u32 u = __float_as_uint(x);
    u32 r = u + 0x7FFFu + ((u >> 16) & 1u);
    return (u16)(r >> 16);
}

__device__ __forceinline__ void gl_lds16(const void* g, void* l) {
    __builtin_amdgcn_global_load_lds((const __attribute__((address_space(1))) u32*)g,
                                     (__attribute__((address_space(3))) u32*)l,
                                     16, 0, 0);
}

__device__ __forceinline__ u64 umin64(u64 a, u64 b) { return a < b ? a : b; }

// ---------------------------------------------------------------------------
// Kernel 1: prep. Blocks [0,16384): z -> z_hi bf16.
// Blocks [16384,18432): emb -> e_hi bf16 + ||e||^2 (one wave per code).
// ---------------------------------------------------------------------------
__global__ __launch_bounds__(256) void vq_prep(
    const float4* __restrict__ z4, ushort4* __restrict__ zh,
    const float* __restrict__ emb, ushort4* __restrict__ eh,
    float* __restrict__ e_norms) {
    int b = blockIdx.x;
    if (b < (M_ROWS * DDIM) / 1024) {
        int i = b * 256 + threadIdx.x;
        float4 v = z4[i];
        ushort4 h;
        h.x = bf16_rne(v.x); h.y = bf16_rne(v.y);
        h.z = bf16_rne(v.z); h.w = bf16_rne(v.w);
        zh[i] = h;
    } else {
        int wave = threadIdx.x >> 6;
        int lane = threadIdx.x & 63;
        int code = (b - (M_ROWS * DDIM) / 1024) * 4 + wave;
        const float4* ep = (const float4*)(emb + (size_t)code * DDIM);
        size_t base4 = (size_t)code * (DDIM / 4);
        float s = 0.f;
        #pragma unroll
        for (int j = 0; j < 2; ++j) {
            int c = lane + 64 * j;
            float4 e = ep[c];
            s += e.x * e.x + e.y * e.y + e.z * e.z + e.w * e.w;
            ushort4 h;
            h.x = bf16_rne(e.x); h.y = bf16_rne(e.y);
            h.z = bf16_rne(e.z); h.w = bf16_rne(e.w);
            eh[base4 + c] = h;
        }
        #pragma unroll
        for (int off = 32; off; off >>= 1) s += __shfl_down(s, off, 64);
        if (lane == 0) e_norms[code] = s;
    }
}

// ---------------------------------------------------------------------------
// Kernel 2: phase-1 coarse GEMM (bf16 hi*hi) + per-(row, 32-col-chunk) minima.
// R2-verified structure: 128x128 tile, BK=32, 4 waves 2x2, 4x4 frags of
// 16x16x32. Each (row,chunk) owned by exactly one wave -> plain stores.
// ---------------------------------------------------------------------------
__global__ __launch_bounds__(256) void vq_phase1(
    const u16* __restrict__ z_hi, const u16* __restrict__ e_hi,
    const float* __restrict__ e_norms,
    float* __restrict__ chunkmin) {
    __shared__ __align__(16) u16 ldsA[128][32];   // 8 KB
    __shared__ __align__(16) u16 ldsB[128][32];   // 8 KB

    const int tid  = threadIdx.x;
    const int wave = tid >> 6;
    const int lane = tid & 63;
    const int wm   = wave & 1;
    const int wn   = wave >> 1;
    const int row0 = blockIdx.x * 128;
    const int col0 = blockIdx.y * 128;

    const int srow = (wave << 5) + (lane >> 2);
    const int scol = (lane & 3) << 3;
    const u16* gA = z_hi + (size_t)(row0 + srow) * DDIM + scol;
    const u16* gB = e_hi + (size_t)(col0 + srow) * DDIM + scol;

    const int fm = (wm << 6) + (lane & 15);
    const int fn = (wn << 6) + (lane & 15);
    const int fk = (lane >> 4) << 3;

    f32x4 acc[4][4] = {};

    for (int it = 0; it < 16; ++it) {
        const int d0 = it << 5;
        __syncthreads();
        #pragma unroll
        for (int s = 0; s < 2; ++s) {
            const size_t go = (size_t)d0 + (size_t)s * 16 * DDIM;
            const int lr = (wave << 5) + (s << 4);
            gl_lds16(gA + go, &ldsA[lr][0]);
            gl_lds16(gB + go, &ldsB[lr][0]);
        }
        __syncthreads();

        short8 ah[4], bh[4];
        #pragma unroll
        for (int i = 0; i < 4; ++i) ah[i] = *(const short8*)&ldsA[fm + i * 16][fk];
        #pragma unroll
        for (int j = 0; j < 4; ++j) bh[j] = *(const short8*)&ldsB[fn + j * 16][fk];
        #pragma unroll
        for (int i = 0; i < 4; ++i)
            #pragma unroll
            for (int j = 0; j < 4; ++j)
                acc[i][j] = __builtin_amdgcn_mfma_f32_16x16x32_bf16(ah[i], bh[j], acc[i][j], 0, 0, 0);
    }

    // epilogue: C layout col = lane&15, row = (lane>>4)*4 + reg.
    const int cn = lane & 15;
    const int cg = lane >> 4;
    float en[4];
    #pragma unroll
    for (int j = 0; j < 4; ++j) en[j] = e_norms[col0 + (wn << 6) + j * 16 + cn];

    #pragma unroll
    for (int i = 0; i < 4; ++i)
        #pragma unroll
        for (int r = 0; r < 4; ++r) {
            float d0v = en[0] - 2.0f * acc[i][0][r];
            float d1v = en[1] - 2.0f * acc[i][1][r];
            float d2v = en[2] - 2.0f * acc[i][2][r];
            float d3v = en[3] - 2.0f * acc[i][3][r];
            float m01 = fminf(d0v, d1v);
            float m23 = fminf(d2v, d3v);
            #pragma unroll
            for (int off = 1; off < 16; off <<= 1) {
                m01 = fminf(m01, __shfl_xor(m01, off, 64));
                m23 = fminf(m23, __shfl_xor(m23, off, 64));
            }
            if (cn == 0) {
                int row_g = row0 + (wm << 6) + i * 16 + (cg << 2) + r;
                int cbase = row_g * NCHUNK + (blockIdx.y << 2) + (wn << 1);
                chunkmin[cbase]     = m01;
                chunkmin[cbase + 1] = m23;
            }
        }
}

// ---------------------------------------------------------------------------
// Kernel 3: fused finalize. One wave per row:
//  - min over 256 chunk-minima -> threshold
//  - ballot -> uniform candidate-chunk masks (no atomics, no queue)
//  - exact fp32 re-eval of candidate chunks (z row held in registers)
//  - gather emb[winner] -> out_q, out_idx, per-block loss partial
// ---------------------------------------------------------------------------
__global__ __launch_bounds__(256) void vq_finalize_rows(
    const float* __restrict__ z, const float* __restrict__ emb,
    const float* __restrict__ e_norms, const float* __restrict__ chunkmin,
    float* __restrict__ out_q, float* __restrict__ out_idx,
    float* __restrict__ partials) {
    const int wave = threadIdx.x >> 6;
    const int lane = threadIdx.x & 63;
    const int row  = blockIdx.x * 4 + wave;

    // ---- threshold from coarse chunk minima ----
    const float4* cm4 = (const float4*)(chunkmin + (size_t)row * NCHUNK);
    float4 v = cm4[lane];
    float m = fminf(fminf(v.x, v.y), fminf(v.z, v.w));
    #pragma unroll
    for (int off = 1; off < 64; off <<= 1) m = fminf(m, __shfl_xor(m, off, 64));
    const float thr = m + MARGIN;

    // ---- z row in registers: lane owns elements [lane*8, lane*8+8) ----
    const float4* z4 = (const float4*)(z + (size_t)row * DDIM);
    float4 za = z4[2 * lane];
    float4 zb = z4[2 * lane + 1];

    // ---- candidate masks (uniform across wave) ----
    u64 msk[4];
    msk[0] = __ballot(v.x <= thr);
    msk[1] = __ballot(v.y <= thr);
    msk[2] = __ballot(v.z <= thr);
    msk[3] = __ballot(v.w <= thr);

    u64 best = 0xFFFFFFFFFFFFFFFFull;
    #pragma unroll
    for (int j = 0; j < 4; ++j) {
        u64 mk = msk[j];
        while (mk) {
            int l = __ffsll((long long)mk) - 1;
            mk &= mk - 1;
            const int chunk = l * 4 + j;
            const int cbase = chunk * 32;
            const float* eb = emb + (size_t)cbase * DDIM + lane * 8;
            float part[32];
            #pragma unroll
            for (int k = 0; k < 32; ++k) {
                float4 ea = *(const float4*)(eb + (size_t)k * DDIM);
                float4 e2 = *(const float4*)(eb + (size_t)k * DDIM + 4);
                part[k] = za.x * ea.x + za.y * ea.y + za.z * ea.z + za.w * ea.w
                        + zb.x * e2.x + zb.y * e2.y + zb.z * e2.z + zb.w * e2.w;
            }
            #pragma unroll
            for (int off = 1; off < 64; off <<= 1)
                #pragma unroll
                for (int k = 0; k < 32; ++k)
                    part[k] += __shfl_xor(part[k], off, 64);
            #pragma unroll
            for (int k = 0; k < 32; ++k) {
                float dist = e_norms[cbase + k] - 2.0f * part[k];
                best = umin64(best, ((u64)float_to_ordered(dist) << 32) | (u32)(cbase + k));
            }
        }
    }

    // ---- gather winner, write outputs, loss partial ----
    const int idx = (int)(best & 0xFFFFFFFFull);
    const float* ew = emb + (size_t)idx * DDIM + lane * 8;
    float4 qa = *(const float4*)ew;
    float4 qb = *(const float4*)(ew + 4);
    float4* op = (float4*)(out_q + (size_t)row * DDIM);
    op[2 * lane]     = qa;
    op[2 * lane + 1] = qb;

    float dx, local = 0.f;
    dx = za.x - qa.x; local += dx * dx;  dx = za.y - qa.y; local += dx * dx;
    dx = za.z - qa.z; local += dx * dx;  dx = za.w - qa.w; local += dx * dx;
    dx = zb.x - qb.x; local += dx * dx;  dx = zb.y - qb.y; local += dx * dx;
    dx = zb.z - qb.z; local += dx * dx;  dx = zb.w - qb.w; local += dx * dx;
    #pragma unroll
    for (int off = 32; off; off >>= 1) local += __shfl_down(local, off, 64);

    __shared__ float wsum[4];
    if (lane == 0) { wsum[wave] = local; out_idx[row] = (float)idx; }
    __syncthreads();
    if (threadIdx.x == 0)
        partials[blockIdx.x] = wsum[0] + wsum[1] + wsum[2] + wsum[3];
}

// ---------------------------------------------------------------------------
// Kernel 4: reduce 4096 loss partials -> scalar loss.
// ---------------------------------------------------------------------------
__global__ __launch_bounds__(256) void vq_loss_reduce(
    const float* __restrict__ partials, float* __restrict__ out_loss) {
    __shared__ float red[256];
    float s = 0.f;
    for (int i = threadIdx.x; i < M_ROWS / 4; i += 256) s += partials[i];
    red[threadIdx.x] = s;
    __syncthreads();
    for (int off = 128; off; off >>= 1) {
        if (threadIdx.x < off) red[threadIdx.x] += red[threadIdx.x + off];
        __syncthreads();
    }
    if (threadIdx.x == 0)
        out_loss[0] = 0.25f * red[0] / ((float)M_ROWS * (float)DDIM);
}

extern "C" void kernel_launch(void* const* d_in, const int* in_sizes, int n_in,
                              void* d_out, int out_size, void* d_ws, size_t ws_size,
                              hipStream_t stream) {
    const float* z   = (const float*)d_in[0];   // [16384, 512]
    const float* emb = (const float*)d_in[1];   // [8192, 512]

    float* out      = (float*)d_out;
    float* out_q    = out;
    float* out_idx  = out + (size_t)M_ROWS * DDIM;
    float* out_loss = out + (size_t)M_ROWS * DDIM + M_ROWS;

    char* ws = (char*)d_ws;
    float* e_norms  = (float*)ws;                         // 32 KB
    float* partials = (float*)(ws + 32768);               // 16 KB
    float* chunkmin = (float*)(ws + 49152);               // 16 MB
    size_t tail     = 49152 + (size_t)M_ROWS * NCHUNK * 4;

    const size_t zbytes = (size_t)M_ROWS * DDIM * 2;   // 16 MB
    const size_t ebytes = (size_t)N_CODES * DDIM * 2;  // 8 MB
    u16 *z_hi, *e_hi;
    if (ws_size >= tail + zbytes + ebytes) {
        z_hi = (u16*)(ws + tail);
        e_hi = (u16*)(ws + tail + zbytes);
    } else {
        // stash bf16 copies in out_q region (33.5 MB >= 24 MB); finalize
        // rewrites out_q after phase1 has consumed them (stream-ordered).
        z_hi = (u16*)out_q;
        e_hi = (u16*)((char*)out_q + zbytes);
    }

    const int zblocks = (M_ROWS * DDIM) / 1024;      // 16384
    const int eblocks = N_CODES / 4;                 // 2048
    vq_prep<<<zblocks + eblocks, 256, 0, stream>>>(
        (const float4*)z, (ushort4*)z_hi, emb, (ushort4*)e_hi, e_norms);

    vq_phase1<<<dim3(M_ROWS / 128, N_CODES / 128), 256, 0, stream>>>(
        z_hi, e_hi, e_norms, chunkmin);

    vq_finalize_rows<<<M_ROWS / 4, 256, 0, stream>>>(
        z, emb, e_norms, chunkmin, out_q, out_idx, partials);

    vq_loss_reduce<<<1, 256, 0, stream>>>(partials, out_loss);
}